// Round 10
// baseline (3403.626 us; speedup 1.0000x reference)
//
#include <hip/hip_runtime.h>
#include <hip/hip_cooperative_groups.h>

namespace cg = cooperative_groups;

// NodeDenoisingADMM: N=20000, FEAT=64, K=4, NNZ=320000, NU=2.0, GAMMA=1.0, J=3
// 14 scan iterations, output = final U (N,FEAT) fp32.
//
// State reduction (GAMMA=1): carried state is v alone.
//   S_t = W_k @ U_t ; Y_t = S_t + v_{t-1} ; Z_t = soft(S_t + Y_t, nu_k d)
//   v_t = Y_t - Z_t ; U_{t+1} = (dm*F - sum_k W_k v_k)/(dm+1), dm = d*mask^2
//
// Node-major CSR: rowid = n*K + k. Edge meta packed in 4 B:
//   [31] sign | [30:26] exp5 (bias 96, 0 => value 0) | [25:17] mant9 (RNE)
//   | [16:15] k | [14:0] col       (rel err 2^-11 < bf16 operand err)
// Scatter is XCD-FILTERED (8 buckets by row/2500, block handles bucket
// blockIdx%8) so cursor/cmeta dirty lines live in ONE XCD's L2.
//
// HISTORY: R1 k-phase wtv: REGRESS. R2 meta pipeline: WIN. R3 NT loads:
// REGRESS. R4/R5 deep gather pipeline: REGRESS (VGPR cliff; TLP > ILP).
// R6 atomic-MLP scatter: REGRESS. R7 two-pass scatter: REGRESS. CSR build
// FROZEN at R2 form. R8 spmm SUB-OWNS-ROW: WIN -90us (cross-lane plumbing
// was the cost). R9 wtv port of R8: WIN -29us (817->788).
// R10: fuse all 27 iteration dispatches into ONE cooperative kernel with
// 27 grid.sync()s. Per-dispatch cost was ~26us vs ~10us work floor ->
// ~200-300us of launch+drain overhead across 27 short dispatches. Phase
// bodies are R8/R9 verbatim (identical accumulation order -> bit-identical
// output), wrapped in grid-stride loops. Grid sized by occupancy query
// (co-residency guaranteed); launch_bounds(256,4) caps VGPR at 128.
// grid.sync() supplies the device-scope fence for cross-XCD handoff.

constexpr int N_    = 20000;
constexpr int FEAT_ = 64;
constexpr int K_    = 4;
constexpr int NNZ_  = 320000;
constexpr int NF    = N_ * FEAT_;     // 1,280,000
constexpr int KN    = K_ * N_;        // 80,000 CSR rows
constexpr int NEDGE = K_ * NNZ_;      // 1,280,000
constexpr int NITER = 14;
constexpr int BLK   = 256;
constexpr int NSB   = (KN + 255) / 256;  // 313 scan blocks
constexpr int NCPY  = 8;                 // hist privatization copies
constexpr int NXCD  = 8;
constexpr int EPV   = 2048;              // edges per scatter block
constexpr int NVB   = NEDGE / EPV;       // 625 virtual blocks

// spmm: 3 nodes per wave-item
constexpr int T_SP  = 3;
constexpr int NW_SP = (N_ + T_SP - 1) / T_SP;             // 6667 wave-items
constexpr int TABSZ = 204;               // 192 slots + skew pad
// wtv: 4 nodes per wave-item, sub owns one node's flat span
constexpr int NW_WT = N_ / 4;            // 5000 wave-items
constexpr int WCAP  = 384;               // span capacity (mean 256, +8 sigma)
constexpr int TABW  = WCAP + WCAP / 16;  // 408 skewed slots (= 2*TABSZ)

__device__ __forceinline__ float softf(float x, float t) {
    float a = fabsf(x) - t;
    a = a > 0.0f ? a : 0.0f;
    return copysignf(a, x);
}

__device__ __forceinline__ float bf2f(unsigned short u) {
    union { unsigned int i; float f; } x;
    x.i = ((unsigned int)u) << 16;
    return x.f;
}
__device__ __forceinline__ unsigned short f2bf(float f) {   // RNE
    union { float f; unsigned int i; } x;
    x.f = f;
    unsigned int r = x.i + 0x7FFFu + ((x.i >> 16) & 1u);
    return (unsigned short)(r >> 16);
}

// value bits (fp32) from packed meta
__device__ __forceinline__ unsigned int val_bits(unsigned int p) {
    unsigned int e5 = (p >> 26) & 0x1Fu;
    unsigned int vb = (p & 0x80000000u) | ((e5 + 96u) << 23) |
                      (((p >> 17) & 0x1FFu) << 14);
    return (e5 == 0u) ? 0u : vb;
}

// spmm table entry: low32 = col*16 (ushort4 base), high32 = fp32 val bits
__device__ __forceinline__ unsigned long long enc_tab(unsigned int p) {
    unsigned int c16 = (p & 0x7FFFu) << 4;
    return ((unsigned long long)val_bits(p) << 32) | (unsigned long long)c16;
}

// wtv table entry: low32 = (k*N+col)*16 (full V_bf index), high32 = val
__device__ __forceinline__ unsigned long long enc_wtv(unsigned int p) {
    unsigned int c16 = (((p >> 15) & 3u) * (unsigned int)N_ +
                        (p & 0x7FFFu)) << 4;
    return ((unsigned long long)val_bits(p) << 32) | (unsigned long long)c16;
}

__device__ __forceinline__ void fma4(float4& acc, float v, const ushort4& x) {
    acc.x += v * bf2f(x.x);
    acc.y += v * bf2f(x.y);
    acc.z += v * bf2f(x.z);
    acc.w += v * bf2f(x.w);
}

// ---------------- CSR build + precompute ----------------

// dm[n] = d*mask^2 ; F_bf = bf16(F)
__global__ __launch_bounds__(BLK) void precompute_kernel(
    const float* __restrict__ F, const float* __restrict__ d,
    const float* __restrict__ mask, float* __restrict__ dm,
    unsigned short* __restrict__ F_bf) {
    int i = blockIdx.x * BLK + threadIdx.x;       // over NF/4
    if (i >= NF / 4) return;
    float4 f = ((const float4*)F)[i];
    ushort4 o;
    o.x = f2bf(f.x); o.y = f2bf(f.y); o.z = f2bf(f.z); o.w = f2bf(f.w);
    ((ushort4*)F_bf)[i] = o;
    if ((i & (FEAT_ / 4 - 1)) == 0) {
        int n = i / (FEAT_ / 4);
        dm[n] = d[n] * mask[n] * mask[n];
    }
}

// rowid = rows[e]*K + k ; privatized copies (blockIdx&7)
__global__ __launch_bounds__(BLK) void hist_kernel(
    const int* __restrict__ rows, int* __restrict__ cnt8) {
    int e = blockIdx.x * BLK + threadIdx.x;
    if (e >= NEDGE) return;
    int k = e / NNZ_;
    int copy = blockIdx.x & (NCPY - 1);
    atomicAdd(&cnt8[copy * KN + rows[e] * K_ + k], 1);
}

// block-local exclusive scan over summed copies + block sums
__global__ __launch_bounds__(256) void scan1_kernel(
    const int* __restrict__ cnt8, int* __restrict__ loc,
    int* __restrict__ bsum) {
    int i = blockIdx.x * 256 + threadIdx.x;
    int x = 0;
    if (i < KN) {
        #pragma unroll
        for (int c = 0; c < NCPY; ++c) x += cnt8[c * KN + i];
    }
    int lane = threadIdx.x & 63, wid = threadIdx.x >> 6;
    int v = x;
    #pragma unroll
    for (int off = 1; off < 64; off <<= 1) {
        int t = __shfl_up(v, off, 64);
        if (lane >= off) v += t;
    }
    __shared__ int ws[4];
    if (lane == 63) ws[wid] = v;
    __syncthreads();
    int add = 0;
    for (int u = 0; u < wid; ++u) add += ws[u];
    v += add;
    if (i < KN) loc[i] = v - x;
    if (threadIdx.x == 255) bsum[blockIdx.x] = v;
}

__global__ __launch_bounds__(512) void scan2_kernel(int* __restrict__ bsum) {
    int tid = threadIdx.x;
    int x = (tid < NSB) ? bsum[tid] : 0;
    int lane = tid & 63, wid = tid >> 6;
    int v = x;
    #pragma unroll
    for (int off = 1; off < 64; off <<= 1) {
        int t = __shfl_up(v, off, 64);
        if (lane >= off) v += t;
    }
    __shared__ int ws[8];
    if (lane == 63) ws[wid] = v;
    __syncthreads();
    int add = 0;
    for (int u = 0; u < wid; ++u) add += ws[u];
    v += add;
    if (tid < NSB) bsum[tid] = v - x;
}

__global__ __launch_bounds__(256) void scan3_kernel(
    const int* __restrict__ loc, const int* __restrict__ bsum,
    int* __restrict__ offs, int* __restrict__ cursor) {
    int i = blockIdx.x * 256 + threadIdx.x;
    if (i < KN) {
        int v = loc[i] + bsum[blockIdx.x];
        offs[i] = v;
        cursor[i] = v;
    }
    if (i == 0) offs[KN] = NEDGE;
}

// XCD-filtered scatter (R2 form — frozen; R3/R6/R7 variants all regressed).
__global__ __launch_bounds__(BLK) void scatter_kernel(
    const int* __restrict__ rows, const int* __restrict__ cols,
    const float* __restrict__ vals, int* __restrict__ cursor,
    unsigned int* __restrict__ cmeta) {
    int xcd = blockIdx.x & (NXCD - 1);
    int vb  = blockIdx.x >> 3;
    int ebase = vb * EPV;
    #pragma unroll
    for (int i = 0; i < EPV / BLK; ++i) {
        int e = ebase + i * BLK + threadIdx.x;
        int row = rows[e];
        if (row / (N_ / NXCD) != xcd) continue;
        int k = e / NNZ_;
        unsigned int b  = __float_as_uint(vals[e]);
        unsigned int rb = b + 0x1FFFu + ((b >> 14) & 1u);  // RNE to 9 mant
        int exp8 = (int)((rb >> 23) & 0xFF);
        unsigned int pk = 0u;
        if (exp8 > 96)                                     // else flush to 0
            pk = (b & 0x80000000u) | ((unsigned int)(exp8 - 96) << 26) |
                 (((rb >> 14) & 0x1FFu) << 17);
        pk |= ((unsigned int)k << 15) | (unsigned int)cols[e];
        int pos = atomicAdd(&cursor[row * K_ + k], 1);
        cmeta[pos] = pk;
    }
}

// ---------------- fused iteration phases (R8/R9 bodies verbatim) ----------------

// spmm phase: wave-item = node n0..n0+2; sub (lane>>4) == k owns row n*4+k.
// Cooperative span load -> skewed LDS table (col*16, v) -> sub walks its
// own row (ds_read_b64 same-slot broadcast). No bpermute, no butterfly.
__device__ __forceinline__ void spmm_phase(
    bool first, const int* __restrict__ offs,
    const unsigned int* __restrict__ cmeta,
    const ushort4* __restrict__ X4, const float* __restrict__ d,
    ushort4* __restrict__ V4, unsigned long long* Tw,
    int lane, int sub, int q, int w0, int gw) {
    float nu_s = sub == 0 ? 0.0f : (sub == 1 ? 2.0f : (sub == 2 ? 0.5f : 0.125f));
    for (int wv = w0; wv < NW_SP; wv += gw) {
        int n0 = wv * T_SP;
        int off_l = 0;
        if (lane <= 4 * T_SP) {          // 13 offsets
            int i = n0 * K_ + lane;
            if (i > KN) i = KN;
            off_l = offs[i];
        }
        // prologue: tile 0 span + raw meta
        int tb = __shfl(off_l, 0, 64);
        int te = __shfl(off_l, 4, 64);
        int span = te - tb;
        unsigned int pA = 0, pB = 0, pC = 0;
        if (lane < span)       pA = cmeta[tb + lane];
        if (64 + lane < span)  pB = cmeta[tb + 64 + lane];
        if (128 + lane < span) pC = cmeta[tb + 128 + lane];
        #pragma unroll
        for (int t = 0; t < T_SP; ++t) {
            int n = n0 + t;
            if (n >= N_) break;
            unsigned long long* Tc = Tw + (t & 1) * TABSZ;
            int bs = __shfl(off_l, 4 * t + sub, 64);
            int es = __shfl(off_l, 4 * t + sub + 1, 64);
            int pre = bs - tb;
            int cnt = es - bs;
            int jmax = 192 - pre;
            jmax = cnt < jmax ? cnt : jmax;
            if (jmax < 0) jmax = 0;
            int maxc = jmax;
            { int o1 = __shfl_xor(maxc, 16, 64); maxc = maxc > o1 ? maxc : o1;
              int o2 = __shfl_xor(maxc, 32, 64); maxc = maxc > o2 ? maxc : o2; }
            if (lane < span)       { int s = lane;       Tc[s + (s >> 4)] = enc_tab(pA); }
            if (64 + lane < span)  { int s = 64 + lane;  Tc[s + (s >> 4)] = enc_tab(pB); }
            if (128 + lane < span) { int s = 128 + lane; Tc[s + (s >> 4)] = enc_tab(pC); }
            int tbn = te, ten = te, spann = 0;
            unsigned int nA = 0, nB = 0, nC = 0;
            if (t + 1 < T_SP && n + 1 < N_) {
                ten = __shfl(off_l, 4 * t + 8, 64);
                spann = ten - tbn;
                if (lane < spann)       nA = cmeta[tbn + lane];
                if (64 + lane < spann)  nB = cmeta[tbn + 64 + lane];
                if (128 + lane < spann) nC = cmeta[tbn + 128 + lane];
            }
            asm volatile("s_waitcnt lgkmcnt(0)" ::: "memory");
            float4 acc = {0.f, 0.f, 0.f, 0.f};
            for (int i0 = 0; i0 < maxc; i0 += 4) {
                float vv[4]; int cc[4];
                #pragma unroll
                for (int u = 0; u < 4; ++u) {
                    int j = i0 + u;
                    bool ok = j < jmax;
                    int slot = ok ? pre + j : 0;
                    unsigned long long e = Tc[slot + (slot >> 4)];
                    cc[u] = (int)(unsigned int)e;
                    vv[u] = ok ? __uint_as_float((unsigned int)(e >> 32)) : 0.0f;
                }
                ushort4 xx[4];
                #pragma unroll
                for (int u = 0; u < 4; ++u) xx[u] = X4[cc[u] + q];
                #pragma unroll
                for (int u = 0; u < 4; ++u) fma4(acc, vv[u], xx[u]);
            }
            if (span > 192) {            // never in practice
                for (int e = tb + 192; e < te; ++e) {
                    unsigned int p = cmeta[e];
                    int ke = (int)((p >> 15) & 3u);
                    unsigned long long en = enc_tab(p);
                    if (sub == ke) {
                        ushort4 x = X4[(int)(unsigned int)en + q];
                        fma4(acc, __uint_as_float((unsigned int)(en >> 32)), x);
                    }
                }
            }
            {
                float dn = d[n];
                int idx4 = (sub * N_ + n) * (FEAT_ / 4) + q;
                float thr = nu_s * dn;
                float4 y;
                if (first) {
                    y = make_float4(0.f, 0.f, 0.f, 0.f);
                } else {
                    ushort4 vp = V4[idx4];
                    y.x = acc.x + bf2f(vp.x); y.y = acc.y + bf2f(vp.y);
                    y.z = acc.z + bf2f(vp.z); y.w = acc.w + bf2f(vp.w);
                }
                ushort4 o;
                o.x = f2bf(y.x - softf(acc.x + y.x, thr));
                o.y = f2bf(y.y - softf(acc.y + y.y, thr));
                o.z = f2bf(y.z - softf(acc.z + y.z, thr));
                o.w = f2bf(y.w - softf(acc.w + y.w, thr));
                V4[idx4] = o;
            }
            tb = tbn; te = ten; span = spann;
            pA = nA; pB = nB; pC = nC;
        }
    }
}

// wtv phase: wave-item = 4 nodes; sub owns node n0+sub entirely.
// Cooperative union-span load -> skewed LDS table with full V index ->
// sub walks its node. No butterfly; epilogue wave-wide coalesced.
__device__ __forceinline__ void wtv_phase(
    bool last, const int* __restrict__ offs,
    const unsigned int* __restrict__ cmeta,
    const ushort4* __restrict__ V4, const float* __restrict__ F,
    const float* __restrict__ dm, float* __restrict__ U,
    unsigned short* __restrict__ U_bf, unsigned long long* Tw,
    int lane, int sub, int q, int w0, int gw) {
    for (int wv = w0; wv < NW_WT; wv += gw) {
        int n0 = wv * 4;
        int off_l = 0;
        if (lane <= 16) {                // 17 offsets spanning 4 nodes
            int i = n0 * K_ + lane;
            if (i > KN) i = KN;
            off_l = offs[i];
        }
        int tb = __shfl(off_l, 0, 64);
        int te = __shfl(off_l, 16, 64);
        int span = te - tb;
        unsigned int pr[6];
        #pragma unroll
        for (int c = 0; c < 6; ++c) {
            pr[c] = 0u;
            if (c * 64 + lane < span) pr[c] = cmeta[tb + c * 64 + lane];
        }
        int bs = __shfl(off_l, 4 * sub, 64);
        int es = __shfl(off_l, 4 * sub + 4, 64);
        int pre = bs - tb;
        int cnt = es - bs;
        int jmax = WCAP - pre;
        jmax = cnt < jmax ? cnt : jmax;
        if (jmax < 0) jmax = 0;
        int maxc = jmax;
        { int o1 = __shfl_xor(maxc, 16, 64); maxc = maxc > o1 ? maxc : o1;
          int o2 = __shfl_xor(maxc, 32, 64); maxc = maxc > o2 ? maxc : o2; }
        #pragma unroll
        for (int c = 0; c < 6; ++c) {
            int s = c * 64 + lane;
            if (s < span) Tw[s + (s >> 4)] = enc_wtv(pr[c]);
        }
        asm volatile("s_waitcnt lgkmcnt(0)" ::: "memory");
        float4 acc = {0.f, 0.f, 0.f, 0.f};
        for (int i0 = 0; i0 < maxc; i0 += 4) {
            float vv[4]; int cc[4];
            #pragma unroll
            for (int u = 0; u < 4; ++u) {
                int j = i0 + u;
                bool ok = j < jmax;
                int slot = ok ? pre + j : 0;
                unsigned long long e = Tw[slot + (slot >> 4)];
                cc[u] = (int)(unsigned int)e;
                vv[u] = ok ? __uint_as_float((unsigned int)(e >> 32)) : 0.0f;
            }
            ushort4 xx[4];
            #pragma unroll
            for (int u = 0; u < 4; ++u) xx[u] = V4[cc[u] + q];
            #pragma unroll
            for (int u = 0; u < 4; ++u) fma4(acc, vv[u], xx[u]);
        }
        if (span > WCAP) {               // never in practice
            for (int e = tb + WCAP; e < te; ++e) {
                unsigned int p = cmeta[e];
                unsigned long long en = enc_wtv(p);
                if (e >= bs && e < es) {
                    ushort4 x = V4[(int)(unsigned int)en + q];
                    fma4(acc, __uint_as_float((unsigned int)(en >> 32)), x);
                }
            }
        }
        // barrier before next wave-item overwrites Tw is implicit: the
        // table is re-filled only after all its reads (same wave).
        {
            int n = n0 + sub;
            float dmv = dm[n];
            float r2 = 1.0f / (dmv + 1.0f);
            int idx4 = n * (FEAT_ / 4) + q;
            float4 f = ((const float4*)F)[idx4];
            float4 o;
            o.x = (dmv * f.x - acc.x) * r2; o.y = (dmv * f.y - acc.y) * r2;
            o.z = (dmv * f.z - acc.z) * r2; o.w = (dmv * f.w - acc.w) * r2;
            if (last) ((float4*)U)[idx4] = o;
            ushort4 ob;
            ob.x = f2bf(o.x); ob.y = f2bf(o.y);
            ob.z = f2bf(o.z); ob.w = f2bf(o.w);
            ((ushort4*)U_bf)[idx4] = ob;
        }
    }
}

// one cooperative launch = whole 14-iteration loop; 27 grid.sync()s
// replace 27 kernel launches (launch+drain ~10us each vs sync ~2-4us).
__global__ __launch_bounds__(BLK, 4) void iter_kernel(
    const int* __restrict__ offs, const unsigned int* __restrict__ cmeta,
    const unsigned short* __restrict__ F_bf, const float* __restrict__ d,
    const float* __restrict__ dm, const float* __restrict__ F,
    unsigned short* __restrict__ V_bf, unsigned short* __restrict__ U_bf,
    float* __restrict__ U) {
    __shared__ unsigned long long tab[4][TABW];   // 13 KB; both phases fit
    cg::grid_group grid = cg::this_grid();
    int lane = threadIdx.x & 63;
    int sub  = lane >> 4, q = lane & 15;
    int widx = threadIdx.x >> 6;
    unsigned long long* Tw = tab[widx];
    int gw = gridDim.x * 4;              // wave-items stride
    int w0 = blockIdx.x * 4 + widx;
    const ushort4* X4F = (const ushort4*)F_bf;
    const ushort4* X4U = (const ushort4*)U_bf;
    ushort4* V4 = (ushort4*)V_bf;

    spmm_phase(true, offs, cmeta, X4F, d, V4, Tw, lane, sub, q, w0, gw);
    for (int it = 0; it < NITER; ++it) {
        grid.sync();
        wtv_phase(it == NITER - 1, offs, cmeta, (const ushort4*)V_bf, F, dm,
                  U, U_bf, Tw, lane, sub, q, w0, gw);
        if (it < NITER - 1) {
            grid.sync();
            spmm_phase(false, offs, cmeta, X4U, d, V4, Tw, lane, sub, q, w0, gw);
        }
    }
}

extern "C" void kernel_launch(void* const* d_in, const int* in_sizes, int n_in,
                              void* d_out, int out_size, void* d_ws, size_t ws_size,
                              hipStream_t stream) {
    const float* F      = (const float*)d_in[0];
    const int*   w_rows = (const int*)d_in[1];
    const int*   w_cols = (const int*)d_in[2];
    const float* w_vals = (const float*)d_in[3];
    const float* d      = (const float*)d_in[4];
    const float* mask   = (const float*)d_in[5];
    float* U = (float*)d_out;

    // workspace layout (~29 MB)
    unsigned int* cmeta  = (unsigned int*)d_ws;               // NEDGE u32
    unsigned short* V_bf = (unsigned short*)(cmeta + NEDGE);  // KN*FEAT us
    unsigned short* U_bf = V_bf + (size_t)KN * FEAT_;         // NF us
    unsigned short* F_bf = U_bf + NF;                         // NF us
    float* dm     = (float*)(F_bf + NF);                      // N
    int*   cnt8   = (int*)(dm + N_);                          // NCPY*KN
    int*   loc    = cnt8 + NCPY * KN;                         // KN
    int*   bsum   = loc + KN;                                 // pad 512
    int*   offs   = bsum + 512;                               // KN+1
    int*   cursor = offs + KN + 1;                            // KN

    const int gEdge = NEDGE / BLK;                // 5000
    const int gNF4  = (NF / 4) / BLK;             // 1250

    // ---- CSR build + precompute ----
    hipMemsetAsync(cnt8, 0, (size_t)NCPY * KN * 4, stream);
    precompute_kernel<<<gNF4, BLK, 0, stream>>>(F, d, mask, dm, F_bf);
    hist_kernel<<<gEdge, BLK, 0, stream>>>(w_rows, cnt8);
    scan1_kernel<<<NSB, 256, 0, stream>>>(cnt8, loc, bsum);
    scan2_kernel<<<1, 512, 0, stream>>>(bsum);
    scan3_kernel<<<NSB, 256, 0, stream>>>(loc, bsum, offs, cursor);
    scatter_kernel<<<NVB * NXCD, BLK, 0, stream>>>(w_rows, w_cols, w_vals,
                                                   cursor, cmeta);

    // ---- iterations: one cooperative launch ----
    static int nblk_co = 0;
    if (nblk_co == 0) {
        int per_cu = 0;
        hipOccupancyMaxActiveBlocksPerMultiprocessor(&per_cu, iter_kernel,
                                                     BLK, 0);
        if (per_cu < 1) per_cu = 1;
        if (per_cu > 8) per_cu = 8;
        nblk_co = per_cu * 256;          // 256 CUs on MI355X (gfx950)
    }
    const int*          a_offs  = offs;
    const unsigned int* a_cmeta = cmeta;
    const unsigned short* a_Fbf = F_bf;
    const float*        a_d     = d;
    const float*        a_dm    = dm;
    const float*        a_F     = F;
    unsigned short*     a_Vbf   = V_bf;
    unsigned short*     a_Ubf   = U_bf;
    float*              a_U     = U;
    void* kargs[] = {(void*)&a_offs, (void*)&a_cmeta, (void*)&a_Fbf,
                     (void*)&a_d, (void*)&a_dm, (void*)&a_F,
                     (void*)&a_Vbf, (void*)&a_Ubf, (void*)&a_U};
    hipLaunchCooperativeKernel((const void*)iter_kernel, dim3(nblk_co),
                               dim3(BLK), kargs, 0, stream);
}

// Round 11
// 779.650 us; speedup vs baseline: 4.3656x; 4.3656x over previous
//
#include <hip/hip_runtime.h>

// NodeDenoisingADMM: N=20000, FEAT=64, K=4, NNZ=320000, NU=2.0, GAMMA=1.0, J=3
// 14 scan iterations, output = final U (N,FEAT) fp32.
//
// State reduction (GAMMA=1): carried state is v alone.
//   S_t = W_k @ U_t ; Y_t = S_t + v_{t-1} ; Z_t = soft(S_t + Y_t, nu_k d)
//   v_t = Y_t - Z_t ; U_{t+1} = (dm*F - sum_k W_k v_k)/(dm+1), dm = d*mask^2
//
// Node-major CSR: rowid = n*K + k. Edge meta packed in 4 B:
//   [31] sign | [30:26] exp5 (bias 96, 0 => value 0) | [25:17] mant9 (RNE)
//   | [16:15] k | [14:0] col       (rel err 2^-11 < bf16 operand err)
// Scatter is XCD-FILTERED (8 buckets by row/2500, block handles bucket
// blockIdx%8) so cursor/cmeta dirty lines live in ONE XCD's L2.
//
// HISTORY: R1 k-phase wtv: REGRESS. R2 meta pipeline: WIN. R3 NT loads:
// REGRESS. R4/R5 deep gather pipeline: REGRESS (VGPR cliff; TLP > ILP).
// R6 atomic-MLP scatter: REGRESS. R7 two-pass scatter: REGRESS. CSR build
// FROZEN at R2 form. R8 spmm SUB-OWNS-ROW: WIN -90us. R9 wtv port: WIN
// -29us (817->788). R10 cooperative fusion: REGRESS 3404us — grid.sync
// costs ~196us/sync on MI355X (8192 waves polling across 8 non-coherent
// L2s); ALSO proved launch overhead ~0 under graph replay (fused phase
// work == separate-dispatch total). Phases are ~25us each, latency-bound
// (VALUBusy 7%, HBM 3%): exposed gather-round latency.
// R11: revert to R9 + deepen gather batching 4->6 in both phases (wtv
// dependent rounds 16->11, spmm 6->4; ~+12 live VGPR, far from the
// 64-VGPR occupancy step that killed R4/R5).

constexpr int N_    = 20000;
constexpr int FEAT_ = 64;
constexpr int K_    = 4;
constexpr int NNZ_  = 320000;
constexpr int NF    = N_ * FEAT_;     // 1,280,000
constexpr int KN    = K_ * N_;        // 80,000 CSR rows
constexpr int NEDGE = K_ * NNZ_;      // 1,280,000
constexpr int NITER = 14;
constexpr int BLK   = 256;
constexpr int NSB   = (KN + 255) / 256;  // 313 scan blocks
constexpr int NCPY  = 8;                 // hist privatization copies
constexpr int NXCD  = 8;
constexpr int EPV   = 2048;              // edges per scatter block
constexpr int NVB   = NEDGE / EPV;       // 625 virtual blocks

// spmm4: 3 nodes (tiles) per wave -> 12 CSR rows/wave
constexpr int T_SP  = 3;
constexpr int NW_SP = (N_ + T_SP - 1) / T_SP;             // 6667 waves
constexpr int NB_SP4 = (NW_SP + 3) / 4;                   // 1667 blocks
constexpr int TABSZ = 204;               // 192 slots + skew pad

// wtv4: 4 nodes per wave, sub owns one node's flat span
constexpr int NB_WT4 = ((N_ / 4) + 3) / 4;                // 1250 blocks
constexpr int WCAP  = 384;               // span capacity (mean 256, +8 sigma)
constexpr int TABW  = WCAP + WCAP / 16;  // 408 skewed slots

constexpr int GB    = 6;                 // gather batch depth (R11: 4->6)

__constant__ float c_nu[4] = {0.0f, 2.0f, 0.5f, 0.125f};

__device__ __forceinline__ float softf(float x, float t) {
    float a = fabsf(x) - t;
    a = a > 0.0f ? a : 0.0f;
    return copysignf(a, x);
}

__device__ __forceinline__ float bf2f(unsigned short u) {
    union { unsigned int i; float f; } x;
    x.i = ((unsigned int)u) << 16;
    return x.f;
}
__device__ __forceinline__ unsigned short f2bf(float f) {   // RNE
    union { float f; unsigned int i; } x;
    x.f = f;
    unsigned int r = x.i + 0x7FFFu + ((x.i >> 16) & 1u);
    return (unsigned short)(r >> 16);
}

// value bits (fp32) from packed meta
__device__ __forceinline__ unsigned int val_bits(unsigned int p) {
    unsigned int e5 = (p >> 26) & 0x1Fu;
    unsigned int vb = (p & 0x80000000u) | ((e5 + 96u) << 23) |
                      (((p >> 17) & 0x1FFu) << 14);
    return (e5 == 0u) ? 0u : vb;
}

// spmm table entry: low32 = col*16 (ushort4 base), high32 = fp32 val bits
__device__ __forceinline__ unsigned long long enc_tab(unsigned int p) {
    unsigned int c16 = (p & 0x7FFFu) << 4;
    return ((unsigned long long)val_bits(p) << 32) | (unsigned long long)c16;
}

// wtv table entry: low32 = (k*N+col)*16 (full V_bf index), high32 = val
__device__ __forceinline__ unsigned long long enc_wtv(unsigned int p) {
    unsigned int c16 = (((p >> 15) & 3u) * (unsigned int)N_ +
                        (p & 0x7FFFu)) << 4;
    return ((unsigned long long)val_bits(p) << 32) | (unsigned long long)c16;
}

__device__ __forceinline__ void fma4(float4& acc, float v, const ushort4& x) {
    acc.x += v * bf2f(x.x);
    acc.y += v * bf2f(x.y);
    acc.z += v * bf2f(x.z);
    acc.w += v * bf2f(x.w);
}

// ---------------- CSR build + precompute ----------------

// dm[n] = d*mask^2 ; F_bf = bf16(F)
__global__ __launch_bounds__(BLK) void precompute_kernel(
    const float* __restrict__ F, const float* __restrict__ d,
    const float* __restrict__ mask, float* __restrict__ dm,
    unsigned short* __restrict__ F_bf) {
    int i = blockIdx.x * BLK + threadIdx.x;       // over NF/4
    if (i >= NF / 4) return;
    float4 f = ((const float4*)F)[i];
    ushort4 o;
    o.x = f2bf(f.x); o.y = f2bf(f.y); o.z = f2bf(f.z); o.w = f2bf(f.w);
    ((ushort4*)F_bf)[i] = o;
    if ((i & (FEAT_ / 4 - 1)) == 0) {
        int n = i / (FEAT_ / 4);
        dm[n] = d[n] * mask[n] * mask[n];
    }
}

// rowid = rows[e]*K + k ; privatized copies (blockIdx&7)
__global__ __launch_bounds__(BLK) void hist_kernel(
    const int* __restrict__ rows, int* __restrict__ cnt8) {
    int e = blockIdx.x * BLK + threadIdx.x;
    if (e >= NEDGE) return;
    int k = e / NNZ_;
    int copy = blockIdx.x & (NCPY - 1);
    atomicAdd(&cnt8[copy * KN + rows[e] * K_ + k], 1);
}

// block-local exclusive scan over summed copies + block sums
__global__ __launch_bounds__(256) void scan1_kernel(
    const int* __restrict__ cnt8, int* __restrict__ loc,
    int* __restrict__ bsum) {
    int i = blockIdx.x * 256 + threadIdx.x;
    int x = 0;
    if (i < KN) {
        #pragma unroll
        for (int c = 0; c < NCPY; ++c) x += cnt8[c * KN + i];
    }
    int lane = threadIdx.x & 63, wid = threadIdx.x >> 6;
    int v = x;
    #pragma unroll
    for (int off = 1; off < 64; off <<= 1) {
        int t = __shfl_up(v, off, 64);
        if (lane >= off) v += t;
    }
    __shared__ int ws[4];
    if (lane == 63) ws[wid] = v;
    __syncthreads();
    int add = 0;
    for (int u = 0; u < wid; ++u) add += ws[u];
    v += add;
    if (i < KN) loc[i] = v - x;
    if (threadIdx.x == 255) bsum[blockIdx.x] = v;
}

__global__ __launch_bounds__(512) void scan2_kernel(int* __restrict__ bsum) {
    int tid = threadIdx.x;
    int x = (tid < NSB) ? bsum[tid] : 0;
    int lane = tid & 63, wid = tid >> 6;
    int v = x;
    #pragma unroll
    for (int off = 1; off < 64; off <<= 1) {
        int t = __shfl_up(v, off, 64);
        if (lane >= off) v += t;
    }
    __shared__ int ws[8];
    if (lane == 63) ws[wid] = v;
    __syncthreads();
    int add = 0;
    for (int u = 0; u < wid; ++u) add += ws[u];
    v += add;
    if (tid < NSB) bsum[tid] = v - x;
}

__global__ __launch_bounds__(256) void scan3_kernel(
    const int* __restrict__ loc, const int* __restrict__ bsum,
    int* __restrict__ offs, int* __restrict__ cursor) {
    int i = blockIdx.x * 256 + threadIdx.x;
    if (i < KN) {
        int v = loc[i] + bsum[blockIdx.x];
        offs[i] = v;
        cursor[i] = v;
    }
    if (i == 0) offs[KN] = NEDGE;
}

// XCD-filtered scatter (R2 form — frozen; R3/R6/R7 variants all regressed).
__global__ __launch_bounds__(BLK) void scatter_kernel(
    const int* __restrict__ rows, const int* __restrict__ cols,
    const float* __restrict__ vals, int* __restrict__ cursor,
    unsigned int* __restrict__ cmeta) {
    int xcd = blockIdx.x & (NXCD - 1);
    int vb  = blockIdx.x >> 3;
    int ebase = vb * EPV;
    #pragma unroll
    for (int i = 0; i < EPV / BLK; ++i) {
        int e = ebase + i * BLK + threadIdx.x;
        int row = rows[e];
        if (row / (N_ / NXCD) != xcd) continue;
        int k = e / NNZ_;
        unsigned int b  = __float_as_uint(vals[e]);
        unsigned int rb = b + 0x1FFFu + ((b >> 14) & 1u);  // RNE to 9 mant
        int exp8 = (int)((rb >> 23) & 0xFF);
        unsigned int pk = 0u;
        if (exp8 > 96)                                     // else flush to 0
            pk = (b & 0x80000000u) | ((unsigned int)(exp8 - 96) << 26) |
                 (((rb >> 14) & 0x1FFu) << 17);
        pk |= ((unsigned int)k << 15) | (unsigned int)cols[e];
        int pos = atomicAdd(&cursor[row * K_ + k], 1);
        cmeta[pos] = pk;
    }
}

// ---------------- iteration kernels ----------------

// spmm4: wave handles T_SP=3 node-tiles; tile = node n = CSR rows
// n*4+k, k=0..3; sub (lane>>4) == k. Per tile: cooperative meta load of
// the flat span [offs[4n], offs[4n+4]) (1-3 chunks), decode once/lane,
// deposit (col*16, v) into skewed LDS table, then each sub serially walks
// its own row: 1 ds_read_b64 per step (broadcast within sub), gather,
// fma — GB=6-deep batched (R11). No bpermute, no butterfly; epilogue
// wave-wide. Meta for tile t+1 prefetched before tile t's steps.
// Span >192 overflow handled by a uniform serial loop (never in practice).
template <bool FIRST>
__global__ __launch_bounds__(BLK) void spmm_fused_kernel(
    const int* __restrict__ offs, const unsigned int* __restrict__ cmeta,
    const unsigned short* __restrict__ Xb,
    const float* __restrict__ d, unsigned short* __restrict__ V_bf) {
    __shared__ unsigned long long tab[4][2][TABSZ];
    int wave = (blockIdx.x * BLK + threadIdx.x) >> 6;
    int lane = threadIdx.x & 63;
    int sub  = lane >> 4, q = lane & 15;
    int widx = threadIdx.x >> 6;
    int n0 = wave * T_SP;
    if (n0 >= N_) return;
    int off_l = 0;
    if (lane <= 4 * T_SP) {              // 13 offsets
        int i = n0 * K_ + lane;
        if (i > KN) i = KN;
        off_l = offs[i];
    }
    const ushort4* X4 = (const ushort4*)Xb;
    ushort4* V4 = (ushort4*)V_bf;
    float nu_s = sub == 0 ? 0.0f : (sub == 1 ? 2.0f : (sub == 2 ? 0.5f : 0.125f));

    // prologue: tile 0 span + raw meta
    int tb = __shfl(off_l, 0, 64);
    int te = __shfl(off_l, 4, 64);
    int span = te - tb;
    unsigned int pA = 0, pB = 0, pC = 0;
    if (lane < span)       pA = cmeta[tb + lane];
    if (64 + lane < span)  pB = cmeta[tb + 64 + lane];
    if (128 + lane < span) pC = cmeta[tb + 128 + lane];

    #pragma unroll
    for (int t = 0; t < T_SP; ++t) {
        int n = n0 + t;
        if (n >= N_) break;
        unsigned long long* Tc = tab[widx][t & 1];
        // per-sub window within the span
        int bs = __shfl(off_l, 4 * t + sub, 64);
        int es = __shfl(off_l, 4 * t + sub + 1, 64);
        int pre = bs - tb;
        int cnt = es - bs;
        int jmax = 192 - pre;
        jmax = cnt < jmax ? cnt : jmax;
        if (jmax < 0) jmax = 0;
        int maxc = jmax;
        { int o1 = __shfl_xor(maxc, 16, 64); maxc = maxc > o1 ? maxc : o1;
          int o2 = __shfl_xor(maxc, 32, 64); maxc = maxc > o2 ? maxc : o2; }
        // decode prefetched meta -> skewed LDS table
        if (lane < span)       { int s = lane;       Tc[s + (s >> 4)] = enc_tab(pA); }
        if (64 + lane < span)  { int s = 64 + lane;  Tc[s + (s >> 4)] = enc_tab(pB); }
        if (128 + lane < span) { int s = 128 + lane; Tc[s + (s >> 4)] = enc_tab(pC); }
        // prefetch next tile's raw meta (flies over this tile's steps)
        int tbn = te, ten = te, spann = 0;
        unsigned int nA = 0, nB = 0, nC = 0;
        if (t + 1 < T_SP && n + 1 < N_) {
            ten = __shfl(off_l, 4 * t + 8, 64);
            spann = ten - tbn;
            if (lane < spann)       nA = cmeta[tbn + lane];
            if (64 + lane < spann)  nB = cmeta[tbn + 64 + lane];
            if (128 + lane < spann) nC = cmeta[tbn + 128 + lane];
        }
        // table writes visible before reads (same wave; explicit drain)
        asm volatile("s_waitcnt lgkmcnt(0)" ::: "memory");
        // steps: each sub walks its own row, GB-deep gather batches
        float4 acc = {0.f, 0.f, 0.f, 0.f};
        for (int i0 = 0; i0 < maxc; i0 += GB) {
            float vv[GB]; int cc[GB];
            #pragma unroll
            for (int u = 0; u < GB; ++u) {
                int j = i0 + u;
                bool ok = j < jmax;
                int slot = ok ? pre + j : 0;
                unsigned long long e = Tc[slot + (slot >> 4)];
                cc[u] = (int)(unsigned int)e;
                vv[u] = ok ? __uint_as_float((unsigned int)(e >> 32)) : 0.0f;
            }
            ushort4 xx[GB];
            #pragma unroll
            for (int u = 0; u < GB; ++u) xx[u] = X4[cc[u] + q];
            #pragma unroll
            for (int u = 0; u < GB; ++u) fma4(acc, vv[u], xx[u]);
        }
        // span >192 overflow: uniform serial walk (never in practice)
        if (span > 192) {
            for (int e = tb + 192; e < te; ++e) {
                unsigned int p = cmeta[e];
                int ke = (int)((p >> 15) & 3u);
                unsigned long long en = enc_tab(p);
                if (sub == ke) {
                    ushort4 x = X4[(int)(unsigned int)en + q];
                    fma4(acc, __uint_as_float((unsigned int)(en >> 32)), x);
                }
            }
        }
        // epilogue: wave-wide (each lane owns 4 feats of row (n, k=sub))
        {
            float dn = d[n];
            int idx4 = (sub * N_ + n) * (FEAT_ / 4) + q;
            float thr = nu_s * dn;
            float4 y;
            if (FIRST) {
                y = make_float4(0.f, 0.f, 0.f, 0.f);
            } else {
                ushort4 vp = V4[idx4];
                y.x = acc.x + bf2f(vp.x); y.y = acc.y + bf2f(vp.y);
                y.z = acc.z + bf2f(vp.z); y.w = acc.w + bf2f(vp.w);
            }
            ushort4 o;
            o.x = f2bf(y.x - softf(acc.x + y.x, thr));
            o.y = f2bf(y.y - softf(acc.y + y.y, thr));
            o.z = f2bf(y.z - softf(acc.z + y.z, thr));
            o.w = f2bf(y.w - softf(acc.w + y.w, thr));
            V4[idx4] = o;
        }
        // rotate pipeline state
        tb = tbn; te = ten; span = spann;
        pA = nA; pB = nB; pC = nC;
    }
}

// wtv4: wave = 4 nodes; sub owns node n0+sub entirely (flat span over all
// k, mean 64 edges — NOT subdivided). Cooperative load of the 4-node union
// span (mean 256, cap 384 = +8 sigma), decode once/lane into skewed LDS
// table with FULL gather index (k*N+col)*16; sub walks its own node
// GB=6-deep batched (R11: rounds 16->11). No butterfly. Epilogue
// wave-wide: 64 consecutive float4/ushort4 stores (coalesced).
// U = (dm*F - acc)/(dm+1); fp32 U stored ONLY when LAST; bf16 always.
template <bool LAST>
__global__ __launch_bounds__(BLK) void wtv_u_kernel(
    const int* __restrict__ offs, const unsigned int* __restrict__ cmeta,
    const unsigned short* __restrict__ V_bf,
    const float* __restrict__ F, const float* __restrict__ dm,
    float* __restrict__ U, unsigned short* __restrict__ U_bf) {
    __shared__ unsigned long long tab[4][TABW];
    int wave = (blockIdx.x * BLK + threadIdx.x) >> 6;
    int lane = threadIdx.x & 63;
    int sub  = lane >> 4, q = lane & 15;
    int widx = threadIdx.x >> 6;
    int n0 = wave * 4;
    if (n0 >= N_) return;                // N_ % 4 == 0 -> full tiles only
    int off_l = 0;
    if (lane <= 16) {                    // 17 offsets spanning 4 nodes
        int i = n0 * K_ + lane;
        if (i > KN) i = KN;
        off_l = offs[i];
    }
    const ushort4* V4 = (const ushort4*)V_bf;

    int tb = __shfl(off_l, 0, 64);
    int te = __shfl(off_l, 16, 64);
    int span = te - tb;
    // cooperative raw meta load (up to 6 chunks = 384)
    unsigned int pr[6];
    #pragma unroll
    for (int c = 0; c < 6; ++c) {
        pr[c] = 0u;
        if (c * 64 + lane < span) pr[c] = cmeta[tb + c * 64 + lane];
    }
    // per-sub window = its node's full span
    int bs = __shfl(off_l, 4 * sub, 64);
    int es = __shfl(off_l, 4 * sub + 4, 64);
    int pre = bs - tb;
    int cnt = es - bs;
    int jmax = WCAP - pre;
    jmax = cnt < jmax ? cnt : jmax;
    if (jmax < 0) jmax = 0;
    int maxc = jmax;
    { int o1 = __shfl_xor(maxc, 16, 64); maxc = maxc > o1 ? maxc : o1;
      int o2 = __shfl_xor(maxc, 32, 64); maxc = maxc > o2 ? maxc : o2; }
    // decode -> skewed table
    unsigned long long* Tc = tab[widx];
    #pragma unroll
    for (int c = 0; c < 6; ++c) {
        int s = c * 64 + lane;
        if (s < span) Tc[s + (s >> 4)] = enc_wtv(pr[c]);
    }
    asm volatile("s_waitcnt lgkmcnt(0)" ::: "memory");
    // each sub walks its own node, GB-deep gather batches
    float4 acc = {0.f, 0.f, 0.f, 0.f};
    for (int i0 = 0; i0 < maxc; i0 += GB) {
        float vv[GB]; int cc[GB];
        #pragma unroll
        for (int u = 0; u < GB; ++u) {
            int j = i0 + u;
            bool ok = j < jmax;
            int slot = ok ? pre + j : 0;
            unsigned long long e = Tc[slot + (slot >> 4)];
            cc[u] = (int)(unsigned int)e;
            vv[u] = ok ? __uint_as_float((unsigned int)(e >> 32)) : 0.0f;
        }
        ushort4 xx[GB];
        #pragma unroll
        for (int u = 0; u < GB; ++u) xx[u] = V4[cc[u] + q];
        #pragma unroll
        for (int u = 0; u < GB; ++u) fma4(acc, vv[u], xx[u]);
    }
    // span > WCAP overflow: uniform serial walk (never in practice)
    if (span > WCAP) {
        for (int e = tb + WCAP; e < te; ++e) {
            unsigned int p = cmeta[e];
            unsigned long long en = enc_wtv(p);
            if (e >= bs && e < es) {
                ushort4 x = V4[(int)(unsigned int)en + q];
                fma4(acc, __uint_as_float((unsigned int)(en >> 32)), x);
            }
        }
    }
    // epilogue: wave-wide, node n = n0+sub (64 consecutive float4s)
    {
        int n = n0 + sub;
        float dmv = dm[n];
        float r2 = 1.0f / (dmv + 1.0f);
        int idx4 = n * (FEAT_ / 4) + q;
        float4 f = ((const float4*)F)[idx4];
        float4 o;
        o.x = (dmv * f.x - acc.x) * r2; o.y = (dmv * f.y - acc.y) * r2;
        o.z = (dmv * f.z - acc.z) * r2; o.w = (dmv * f.w - acc.w) * r2;
        if (LAST) ((float4*)U)[idx4] = o;
        ushort4 ob;
        ob.x = f2bf(o.x); ob.y = f2bf(o.y);
        ob.z = f2bf(o.z); ob.w = f2bf(o.w);
        ((ushort4*)U_bf)[idx4] = ob;
    }
}

extern "C" void kernel_launch(void* const* d_in, const int* in_sizes, int n_in,
                              void* d_out, int out_size, void* d_ws, size_t ws_size,
                              hipStream_t stream) {
    const float* F      = (const float*)d_in[0];
    const int*   w_rows = (const int*)d_in[1];
    const int*   w_cols = (const int*)d_in[2];
    const float* w_vals = (const float*)d_in[3];
    const float* d      = (const float*)d_in[4];
    const float* mask   = (const float*)d_in[5];
    float* U = (float*)d_out;

    // workspace layout (~29 MB)
    unsigned int* cmeta  = (unsigned int*)d_ws;               // NEDGE u32
    unsigned short* V_bf = (unsigned short*)(cmeta + NEDGE);  // KN*FEAT us
    unsigned short* U_bf = V_bf + (size_t)KN * FEAT_;         // NF us
    unsigned short* F_bf = U_bf + NF;                         // NF us
    float* dm     = (float*)(F_bf + NF);                      // N
    int*   cnt8   = (int*)(dm + N_);                          // NCPY*KN
    int*   loc    = cnt8 + NCPY * KN;                         // KN
    int*   bsum   = loc + KN;                                 // pad 512
    int*   offs   = bsum + 512;                               // KN+1
    int*   cursor = offs + KN + 1;                            // KN

    const int gEdge = NEDGE / BLK;                // 5000
    const int gNF4  = (NF / 4) / BLK;             // 1250

    // ---- CSR build + precompute ----
    hipMemsetAsync(cnt8, 0, (size_t)NCPY * KN * 4, stream);
    precompute_kernel<<<gNF4, BLK, 0, stream>>>(F, d, mask, dm, F_bf);
    hist_kernel<<<gEdge, BLK, 0, stream>>>(w_rows, cnt8);
    scan1_kernel<<<NSB, 256, 0, stream>>>(cnt8, loc, bsum);
    scan2_kernel<<<1, 512, 0, stream>>>(bsum);
    scan3_kernel<<<NSB, 256, 0, stream>>>(loc, bsum, offs, cursor);
    scatter_kernel<<<NVB * NXCD, BLK, 0, stream>>>(w_rows, w_cols, w_vals,
                                                   cursor, cmeta);

    // ---- iterations ----
    spmm_fused_kernel<true><<<NB_SP4, BLK, 0, stream>>>(offs, cmeta, F_bf, d, V_bf);
    for (int it = 0; it < NITER; ++it) {
        if (it < NITER - 1) {
            wtv_u_kernel<false><<<NB_WT4, BLK, 0, stream>>>(offs, cmeta, V_bf,
                                                            F, dm, U, U_bf);
            spmm_fused_kernel<false><<<NB_SP4, BLK, 0, stream>>>(offs, cmeta,
                                                                 U_bf, d, V_bf);
        } else {
            wtv_u_kernel<true><<<NB_WT4, BLK, 0, stream>>>(offs, cmeta, V_bf,
                                                           F, dm, U, U_bf);
        }
    }
}